// Round 6
// baseline (240.664 us; speedup 1.0000x reference)
//
#include <hip/hip_runtime.h>

#define BDIM 256

constexpr int K      = 32;
constexpr int L1     = 1024;
constexpr int L2C    = 15;
constexpr int L3C    = 32;
constexpr int COUNT  = 9;
constexpr int NF     = 22528;
constexpr int W1COLS = COUNT * (L2C + 1); // 144
constexpr int W2COLS = COUNT * L3C;       // 288

__device__ __forceinline__ float clip01(float x) {
    return fminf(fmaxf(x, 0.0f), 1.0f);
}

// ---- fp32 -> uint8 (excess-128) per-row quantization of W_ft ----
// One wave per row: butterfly-shfl absmax, quantize, pack 4 B/lane/chunk.
// Rebuilt every iteration (workspace re-poisoned; ~25-30 us, near stream floor).
__global__ __launch_bounds__(256) void quant_w_ft(const float* __restrict__ src,
                                                  unsigned char* __restrict__ dst,
                                                  float* __restrict__ scales,
                                                  int nrows) {
    const int wq   = threadIdx.x >> 6;          // wave in block
    const int lane = threadIdx.x & 63;
    const int row  = blockIdx.x * 4 + wq;
    if (row >= nrows) return;

    const float* s = src + (long)row * L1;
    float4 v[4];
    float m = 0.0f;
    #pragma unroll
    for (int i = 0; i < 4; ++i) {
        v[i] = *(const float4*)(s + i * 256 + lane * 4);
        m = fmaxf(m, fmaxf(fmaxf(fabsf(v[i].x), fabsf(v[i].y)),
                           fmaxf(fabsf(v[i].z), fabsf(v[i].w))));
    }
    #pragma unroll
    for (int off = 32; off >= 1; off >>= 1)
        m = fmaxf(m, __shfl_xor(m, off));

    const float mm    = fmaxf(m, 1e-30f);
    const float scale = mm / 127.0f;
    const float inv   = 127.0f / mm;

    unsigned char* d = dst + (long)row * L1;
    #pragma unroll
    for (int i = 0; i < 4; ++i) {
        int q0 = (int)rintf(v[i].x * inv) + 128;
        int q1 = (int)rintf(v[i].y * inv) + 128;
        int q2 = (int)rintf(v[i].z * inv) + 128;
        int q3 = (int)rintf(v[i].w * inv) + 128;
        q0 = max(0, min(255, q0)); q1 = max(0, min(255, q1));
        q2 = max(0, min(255, q2)); q3 = max(0, min(255, q3));
        const unsigned pk = (unsigned)q0 | ((unsigned)q1 << 8) |
                            ((unsigned)q2 << 16) | ((unsigned)q3 << 24);
        *(unsigned*)(d + i * 256 + lane * 4) = pk;
    }
    if (lane == 0) scales[row] = scale;
}

// ---- fused NNUE forward, uint8 table (R4 gather + R6 tail fixes) ----
// R6: R5's 16B-load split regressed (bank conflicts 1.8M->4.7M). Revert to
// R4's 8B/lane gather; attack the tail instead:
//  - accumulators in stride-9 padded LDS (9 odd -> conflict-free writes)
//  - tail remap e = t + 256q -> stride-1 lane access, 8 LDS reads/thread
//  - b1/b2/W3/b3 prefetched at top (latency hides under gather)
//  - final layer merged into t<32 phase via shuffle reduce (no s_p2,
//    fewer barriers, no serial 32-add chain)
__global__ __launch_bounds__(BDIM) void nnue_fused_q(
    const float* __restrict__ us,
    const float* __restrict__ them,
    const int*   __restrict__ wi,
    const float* __restrict__ wv,
    const int*   __restrict__ bi,
    const float* __restrict__ bvv,
    const int*   __restrict__ lsi,
    const unsigned char* __restrict__ Wq,
    const float* __restrict__ scl,
    const float* __restrict__ b_ft,
    const float* __restrict__ W1,
    const float* __restrict__ b1,
    const float* __restrict__ W2,
    const float* __restrict__ b2,
    const float* __restrict__ W3,
    const float* __restrict__ b3,
    float* __restrict__ out)
{
    const int b = blockIdx.x;
    const int t = threadIdx.x;

    __shared__ int   s_idx[2 * K];
    __shared__ float s_val[2 * K];       // val * scale[row]
    __shared__ float s_wp[128 * 9];      // padded: row tc -> tc*9 + j (j<8)
    __shared__ float s_bp[128 * 9];
    __shared__ float s_red[4 * 16];
    __shared__ float s_v[2 * L2C];
    __shared__ float s_l1f;

    // ---- early loads: batch scalars + bucket-dependent prefetches ----
    const int   idx = lsi[b];
    const float u   = us[b];
    const float th  = them[b];

    float b1v = 0.0f, b2v = 0.0f, w3v = 0.0f, b3v = 0.0f;
    if (t < 16) b1v = b1[idx * (L2C + 1) + t];
    if (t < L3C) {
        b2v = b2[idx * L3C + t];
        w3v = W3[t * COUNT + idx];
        b3v = b3[idx];
    }

    // ---- stage sparse indices/values (scale folded into value) ----
    if (t < K) {
        const int ii = wi[b * K + t];
        s_idx[t] = ii;
        s_val[t] = wv[b * K + t] * scl[ii];
    } else if (t < 2 * K) {
        const int ii = bi[b * K + (t - K)];
        s_idx[t] = ii;
        s_val[t] = bvv[b * K + (t - K)] * scl[ii];
    }
    __syncthreads();

    // ---- feature transform: 8 B per row access per lane (R4 proven) ----
    const int   half = t >> 7;        // 0 = white, 1 = black
    const int   tc   = t & 127;
    const int   c8   = tc * 8;        // byte offset == col offset (1 B/col)
    const int*   idxs = s_idx + half * K;
    const float* vals = s_val + half * K;

    float acc[8];
    {
        const float4 bf0 = *(const float4*)(b_ft + c8);
        const float4 bf1 = *(const float4*)(b_ft + c8 + 4);
        acc[0] = bf0.x; acc[1] = bf0.y; acc[2] = bf0.z; acc[3] = bf0.w;
        acc[4] = bf1.x; acc[5] = bf1.y; acc[6] = bf1.z; acc[7] = bf1.w;
    }

    float sumvs = 0.0f;
    #pragma unroll 8
    for (int k = 0; k < K; ++k) {
        const float vs = vals[k];
        const uint2 q  = *(const uint2*)(Wq + ((long)idxs[k] << 10) + c8);
        sumvs += vs;
        acc[0] = fmaf(vs, (float)( q.x        & 0xffu), acc[0]);
        acc[1] = fmaf(vs, (float)((q.x >>  8) & 0xffu), acc[1]);
        acc[2] = fmaf(vs, (float)((q.x >> 16) & 0xffu), acc[2]);
        acc[3] = fmaf(vs, (float)( q.x >> 24        ), acc[3]);
        acc[4] = fmaf(vs, (float)( q.y        & 0xffu), acc[4]);
        acc[5] = fmaf(vs, (float)((q.y >>  8) & 0xffu), acc[5]);
        acc[6] = fmaf(vs, (float)((q.y >> 16) & 0xffu), acc[6]);
        acc[7] = fmaf(vs, (float)( q.y >> 24        ), acc[7]);
    }
    // remove the excess-128 bias in one fma per element
    #pragma unroll
    for (int j = 0; j < 8; ++j) acc[j] = fmaf(sumvs, -128.0f, acc[j]);

    {
        // padded stride-9 store: banks (9*tc + j) % 32, 9 odd -> conflict-free
        float* dst = (half == 0 ? s_wp : s_bp) + tc * 9;
        #pragma unroll
        for (int j = 0; j < 8; ++j) dst[j] = acc[j];
    }
    __syncthreads();

    const float cc = 127.0f / 128.0f;

    // ---- layer 1: this thread owns cols {t, t+256, t+512, t+768} ----
    // padded read: element e lives at (e>>3)*9 + (e&7)
    float wpv[4], bpv[4];
    #pragma unroll
    for (int m = 0; m < 4; ++m) {
        const int e = t + 256 * m;
        const int a = (e >> 3) * 9 + (e & 7);
        wpv[m] = s_wp[a];
        bpv[m] = s_bp[a];
    }

    float A0 = clip01(u * wpv[0] + th * bpv[0]);
    float A1 = clip01(u * wpv[1] + th * bpv[1]);
    float A2 = clip01(u * wpv[2] + th * bpv[2]);
    float A3 = clip01(u * wpv[3] + th * bpv[3]);
    float B0 = clip01(u * bpv[0] + th * wpv[0]);
    float B1 = clip01(u * bpv[1] + th * wpv[1]);
    float B2 = clip01(u * bpv[2] + th * wpv[2]);
    float B3 = clip01(u * bpv[3] + th * wpv[3]);

    // l0p[e] for e = t, t+256, t+512, t+768
    float l0pv[4];
    l0pv[0] = A0 * A2 * cc;   // e<512: A[e]*A[e+512]
    l0pv[1] = A1 * A3 * cc;
    l0pv[2] = B0 * B2 * cc;   // e>=512: Bv[e-512]*Bv[e]
    l0pv[3] = B1 * B3 * cc;

    float p[16];
    #pragma unroll
    for (int j = 0; j < 16; ++j) p[j] = 0.0f;

    const float* W1sel = W1 + idx * (L2C + 1);
    #pragma unroll
    for (int m = 0; m < 4; ++m) {
        const float* wrow = W1sel + (t + 256 * m) * W1COLS;
        const float  lp   = l0pv[m];
        #pragma unroll
        for (int j = 0; j < 16; ++j) p[j] = fmaf(lp, wrow[j], p[j]);
    }

    // wave shuffle-reduce, then combine 4 waves via LDS
    const int lane = t & 63;
    const int wid  = t >> 6;
    #pragma unroll
    for (int j = 0; j < 16; ++j) {
        float v = p[j];
        v += __shfl_down(v, 32);
        v += __shfl_down(v, 16);
        v += __shfl_down(v, 8);
        v += __shfl_down(v, 4);
        v += __shfl_down(v, 2);
        v += __shfl_down(v, 1);
        if (lane == 0) s_red[wid * 16 + j] = v;
    }
    __syncthreads();

    // ---- layers 2+3: all within wave 0, no barriers needed between ----
    if (t < 16) {
        float x1 = s_red[t] + s_red[16 + t] + s_red[32 + t] + s_red[48 + t] + b1v;
        if (t == 15) {
            s_l1f = x1;
        } else {
            float cx = clip01(x1);
            s_v[t]       = cx * cx * cc;
            s_v[L2C + t] = cx * cc;
        }
    }
    // t<16 and t<32 are both wave 0: LDS RAW within a wave is ordered by
    // compiler-inserted lgkmcnt waits; no __syncthreads required.
    if (t < L3C) {
        float acc2 = b2v;
        #pragma unroll
        for (int r = 0; r < 2 * L2C; ++r)
            acc2 = fmaf(s_v[r], W2[r * W2COLS + idx * L3C + t], acc2);
        float pr = clip01(acc2) * w3v;
        // reduce across lanes 0..31 (same wave)
        pr += __shfl_down(pr, 16);
        pr += __shfl_down(pr, 8);
        pr += __shfl_down(pr, 4);
        pr += __shfl_down(pr, 2);
        pr += __shfl_down(pr, 1);
        if (t == 0) out[b] = pr + b3v + s_l1f;
    }
}

// ---- fp32 single-kernel fallback (ws too small) — verified 186 us ----
__global__ __launch_bounds__(BDIM) void nnue_fused_f(
    const float* __restrict__ us,
    const float* __restrict__ them,
    const int*   __restrict__ wi,
    const float* __restrict__ wv,
    const int*   __restrict__ bi,
    const float* __restrict__ bvv,
    const int*   __restrict__ lsi,
    const float* __restrict__ W_ft,
    const float* __restrict__ b_ft,
    const float* __restrict__ W1,
    const float* __restrict__ b1,
    const float* __restrict__ W2,
    const float* __restrict__ b2,
    const float* __restrict__ W3,
    const float* __restrict__ b3,
    float* __restrict__ out)
{
    const int b = blockIdx.x;
    const int t = threadIdx.x;

    __shared__ int   s_idx[2 * K];
    __shared__ float s_val[2 * K];
    __shared__ float s_l0[2 * L1];
    __shared__ float s_red[4 * 16];
    __shared__ float s_v[2 * L2C];
    __shared__ float s_p2[L3C];
    __shared__ float s_l1f;

    if (t < K)          { s_idx[t] = wi[b * K + t];        s_val[t] = wv[b * K + t]; }
    else if (t < 2 * K) { s_idx[t] = bi[b * K + (t - K)];  s_val[t] = bvv[b * K + (t - K)]; }
    __syncthreads();

    const int c4 = t * 4;
    float4 accW = *(const float4*)(b_ft + c4);
    float4 accB = accW;

    #pragma unroll 8
    for (int k = 0; k < K; ++k) {
        const float  vwk = s_val[k];
        const float  vbk = s_val[K + k];
        const float4 rw  = *(const float4*)(W_ft + ((long)s_idx[k]     << 10) + c4);
        const float4 rb  = *(const float4*)(W_ft + ((long)s_idx[K + k] << 10) + c4);
        accW.x = fmaf(vwk, rw.x, accW.x);
        accW.y = fmaf(vwk, rw.y, accW.y);
        accW.z = fmaf(vwk, rw.z, accW.z);
        accW.w = fmaf(vwk, rw.w, accW.w);
        accB.x = fmaf(vbk, rb.x, accB.x);
        accB.y = fmaf(vbk, rb.y, accB.y);
        accB.z = fmaf(vbk, rb.z, accB.z);
        accB.w = fmaf(vbk, rb.w, accB.w);
    }

    const float u  = us[b];
    const float th = them[b];
    float4 A, Bv;
    A.x  = clip01(u * accW.x + th * accB.x);
    A.y  = clip01(u * accW.y + th * accB.y);
    A.z  = clip01(u * accW.z + th * accB.z);
    A.w  = clip01(u * accW.w + th * accB.w);
    Bv.x = clip01(u * accB.x + th * accW.x);
    Bv.y = clip01(u * accB.y + th * accW.y);
    Bv.z = clip01(u * accB.z + th * accW.z);
    Bv.w = clip01(u * accB.w + th * accW.w);
    *(float4*)(s_l0 + c4)      = A;
    *(float4*)(s_l0 + L1 + c4) = Bv;
    __syncthreads();

    const int   idx = lsi[b];
    const float cc  = 127.0f / 128.0f;

    float p[16];
    #pragma unroll
    for (int j = 0; j < 16; ++j) p[j] = 0.0f;

    const float* W1sel = W1 + idx * (L2C + 1);
    #pragma unroll
    for (int q = 0; q < 4; ++q) {
        const int e = c4 + q;
        float l0p;
        if (e < 512) l0p = s_l0[e] * s_l0[e + 512];
        else         l0p = s_l0[e + 512] * s_l0[e + 1024];
        l0p *= cc;
        const float* wrow = W1sel + e * W1COLS;
        #pragma unroll
        for (int j = 0; j < 16; ++j) p[j] = fmaf(l0p, wrow[j], p[j]);
    }

    const int lane = t & 63;
    const int wid  = t >> 6;
    #pragma unroll
    for (int j = 0; j < 16; ++j) {
        float v = p[j];
        v += __shfl_down(v, 32);
        v += __shfl_down(v, 16);
        v += __shfl_down(v, 8);
        v += __shfl_down(v, 4);
        v += __shfl_down(v, 2);
        v += __shfl_down(v, 1);
        if (lane == 0) s_red[wid * 16 + j] = v;
    }
    __syncthreads();

    if (t < 16) {
        float x1 = s_red[t] + s_red[16 + t] + s_red[32 + t] + s_red[48 + t]
                 + b1[idx * (L2C + 1) + t];
        if (t == 15) {
            s_l1f = x1;
        } else {
            float cx = clip01(x1);
            s_v[t]       = cx * cx * cc;
            s_v[L2C + t] = cx * cc;
        }
    }
    __syncthreads();

    if (t < L3C) {
        float acc = b2[idx * L3C + t];
        #pragma unroll
        for (int r = 0; r < 2 * L2C; ++r)
            acc = fmaf(s_v[r], W2[r * W2COLS + idx * L3C + t], acc);
        s_p2[t] = clip01(acc) * W3[t * COUNT + idx];
    }
    __syncthreads();

    if (t == 0) {
        float s = 0.0f;
        #pragma unroll
        for (int m = 0; m < L3C; ++m) s += s_p2[m];
        out[b] = s + b3[idx] + s_l1f;
    }
}

extern "C" void kernel_launch(void* const* d_in, const int* in_sizes, int n_in,
                              void* d_out, int out_size, void* d_ws, size_t ws_size,
                              hipStream_t stream) {
    const float* us   = (const float*)d_in[0];
    const float* them = (const float*)d_in[1];
    const int*   wi   = (const int*)  d_in[2];
    const float* wv   = (const float*)d_in[3];
    const int*   bi   = (const int*)  d_in[4];
    const float* bv   = (const float*)d_in[5];
    const int*   lsi  = (const int*)  d_in[6];
    const float* W_ft = (const float*)d_in[7];
    const float* b_ft = (const float*)d_in[8];
    const float* W1   = (const float*)d_in[9];
    const float* b1   = (const float*)d_in[10];
    const float* W2   = (const float*)d_in[11];
    const float* b2   = (const float*)d_in[12];
    const float* W3   = (const float*)d_in[13];
    const float* b3   = (const float*)d_in[14];
    float*       out  = (float*)d_out;

    const int Bn = in_sizes[0]; // 4096 batch rows
    const size_t qTableBytes = (size_t)NF * L1;                  // 23.1 MB
    const size_t needed      = qTableBytes + (size_t)NF * sizeof(float);

    if (ws_size >= needed) {
        unsigned char* Wq  = (unsigned char*)d_ws;
        float*         scl = (float*)((char*)d_ws + qTableBytes);
        quant_w_ft<<<(NF + 3) / 4, 256, 0, stream>>>(W_ft, Wq, scl, NF);
        nnue_fused_q<<<Bn, BDIM, 0, stream>>>(us, them, wi, wv, bi, bv, lsi,
                                              Wq, scl, b_ft, W1, b1, W2, b2, W3, b3, out);
    } else {
        nnue_fused_f<<<Bn, BDIM, 0, stream>>>(us, them, wi, wv, bi, bv, lsi,
                                              W_ft, b_ft, W1, b1, W2, b2, W3, b3, out);
    }
}

// Round 7
// 231.622 us; speedup vs baseline: 1.0390x; 1.0390x over previous
//
#include <hip/hip_runtime.h>

#define BDIM 256

constexpr int K      = 32;
constexpr int L1     = 1024;
constexpr int L2C    = 15;
constexpr int L3C    = 32;
constexpr int COUNT  = 9;
constexpr int NF     = 22528;
constexpr int W1COLS = COUNT * (L2C + 1); // 144
constexpr int W2COLS = COUNT * L3C;       // 288

__device__ __forceinline__ float clip01(float x) {
    return fminf(fmaxf(x, 0.0f), 1.0f);
}

// single-instruction uint8->float converts (VOP1, gfx9+); removes the
// shift/mask/cvt chains if the compiler wasn't already selecting these.
__device__ __forceinline__ float ub0(unsigned x) { float r; asm("v_cvt_f32_ubyte0 %0, %1" : "=v"(r) : "v"(x)); return r; }
__device__ __forceinline__ float ub1(unsigned x) { float r; asm("v_cvt_f32_ubyte1 %0, %1" : "=v"(r) : "v"(x)); return r; }
__device__ __forceinline__ float ub2(unsigned x) { float r; asm("v_cvt_f32_ubyte2 %0, %1" : "=v"(r) : "v"(x)); return r; }
__device__ __forceinline__ float ub3(unsigned x) { float r; asm("v_cvt_f32_ubyte3 %0, %1" : "=v"(r) : "v"(x)); return r; }

// ---- fp32 -> uint8 (excess-128) per-row quantization of W_ft ----
// R7: lane owns 16 CONSECUTIVE cols -> one uint4 (16 B) store per lane
// (was 4x4B). Loads: 4x float4 at 64B lane stride; all lines fully used
// across the 4 instructions. Wave-wide butterfly absmax unchanged.
__global__ __launch_bounds__(256) void quant_w_ft(const float* __restrict__ src,
                                                  unsigned char* __restrict__ dst,
                                                  float* __restrict__ scales,
                                                  int nrows) {
    const int wq   = threadIdx.x >> 6;          // wave in block
    const int lane = threadIdx.x & 63;
    const int row  = blockIdx.x * 4 + wq;
    if (row >= nrows) return;

    const float* s = src + (long)row * L1 + lane * 16;
    float4 v[4];
    v[0] = *(const float4*)(s);
    v[1] = *(const float4*)(s + 4);
    v[2] = *(const float4*)(s + 8);
    v[3] = *(const float4*)(s + 12);

    float m = 0.0f;
    #pragma unroll
    for (int i = 0; i < 4; ++i)
        m = fmaxf(m, fmaxf(fmaxf(fabsf(v[i].x), fabsf(v[i].y)),
                           fmaxf(fabsf(v[i].z), fabsf(v[i].w))));
    #pragma unroll
    for (int off = 32; off >= 1; off >>= 1)
        m = fmaxf(m, __shfl_xor(m, off));

    const float mm    = fmaxf(m, 1e-30f);
    const float scale = mm / 127.0f;
    const float inv   = 127.0f / mm;

    uint4 pk;
    unsigned* pw = (unsigned*)&pk;
    #pragma unroll
    for (int i = 0; i < 4; ++i) {
        int q0 = (int)rintf(v[i].x * inv) + 128;
        int q1 = (int)rintf(v[i].y * inv) + 128;
        int q2 = (int)rintf(v[i].z * inv) + 128;
        int q3 = (int)rintf(v[i].w * inv) + 128;
        q0 = max(0, min(255, q0)); q1 = max(0, min(255, q1));
        q2 = max(0, min(255, q2)); q3 = max(0, min(255, q3));
        pw[i] = (unsigned)q0 | ((unsigned)q1 << 8) |
                ((unsigned)q2 << 16) | ((unsigned)q3 << 24);
    }
    *(uint4*)(dst + (long)row * L1 + lane * 16) = pk;
    if (lane == 0) scales[row] = scale;
}

// ---- fused NNUE forward, uint8 table (exact R4 structure) ----
// R7: single change vs R4 -- unpack via v_cvt_f32_ubyteN (1 op/byte).
// R4 was the best verified build (fused 71.2 us); R5/R6 tail/layout
// experiments both regressed and are fully reverted.
__global__ __launch_bounds__(BDIM) void nnue_fused_q(
    const float* __restrict__ us,
    const float* __restrict__ them,
    const int*   __restrict__ wi,
    const float* __restrict__ wv,
    const int*   __restrict__ bi,
    const float* __restrict__ bvv,
    const int*   __restrict__ lsi,
    const unsigned char* __restrict__ Wq,
    const float* __restrict__ scl,
    const float* __restrict__ b_ft,
    const float* __restrict__ W1,
    const float* __restrict__ b1,
    const float* __restrict__ W2,
    const float* __restrict__ b2,
    const float* __restrict__ W3,
    const float* __restrict__ b3,
    float* __restrict__ out)
{
    const int b = blockIdx.x;
    const int t = threadIdx.x;

    __shared__ int   s_idx[2 * K];
    __shared__ float s_val[2 * K];   // val * scale[row]
    __shared__ float s_wp[L1];
    __shared__ float s_bp[L1];
    __shared__ float s_red[4 * 16];
    __shared__ float s_v[2 * L2C];
    __shared__ float s_p2[L3C];
    __shared__ float s_l1f;

    // ---- stage sparse indices/values (scale folded into value) ----
    if (t < K) {
        const int ii = wi[b * K + t];
        s_idx[t] = ii;
        s_val[t] = wv[b * K + t] * scl[ii];
    } else if (t < 2 * K) {
        const int ii = bi[b * K + (t - K)];
        s_idx[t] = ii;
        s_val[t] = bvv[b * K + (t - K)] * scl[ii];
    }
    __syncthreads();

    // ---- feature transform: 8 B per row access per lane ----
    const int   half = t >> 7;        // 0 = white, 1 = black
    const int   tc   = t & 127;
    const int   c8   = tc * 8;        // byte offset == col offset (1 B/col)
    const int*   idxs = s_idx + half * K;
    const float* vals = s_val + half * K;

    float acc[8];
    {
        const float4 bf0 = *(const float4*)(b_ft + c8);
        const float4 bf1 = *(const float4*)(b_ft + c8 + 4);
        acc[0] = bf0.x; acc[1] = bf0.y; acc[2] = bf0.z; acc[3] = bf0.w;
        acc[4] = bf1.x; acc[5] = bf1.y; acc[6] = bf1.z; acc[7] = bf1.w;
    }

    float sumvs = 0.0f;
    #pragma unroll 8
    for (int k = 0; k < K; ++k) {
        const float vs = vals[k];
        const uint2 q  = *(const uint2*)(Wq + ((long)idxs[k] << 10) + c8);
        sumvs += vs;
        acc[0] = fmaf(vs, ub0(q.x), acc[0]);
        acc[1] = fmaf(vs, ub1(q.x), acc[1]);
        acc[2] = fmaf(vs, ub2(q.x), acc[2]);
        acc[3] = fmaf(vs, ub3(q.x), acc[3]);
        acc[4] = fmaf(vs, ub0(q.y), acc[4]);
        acc[5] = fmaf(vs, ub1(q.y), acc[5]);
        acc[6] = fmaf(vs, ub2(q.y), acc[6]);
        acc[7] = fmaf(vs, ub3(q.y), acc[7]);
    }
    // remove the excess-128 bias in one fma per element
    #pragma unroll
    for (int j = 0; j < 8; ++j) acc[j] = fmaf(sumvs, -128.0f, acc[j]);

    {
        float* dst = (half == 0 ? s_wp : s_bp) + c8;
        #pragma unroll
        for (int j = 0; j < 8; ++j) dst[j] = acc[j];
    }
    __syncthreads();

    const float u   = us[b];
    const float th  = them[b];
    const int   idx = lsi[b];
    const float cc  = 127.0f / 128.0f;

    // ---- layer 1 ----
    float p[16];
    #pragma unroll
    for (int j = 0; j < 16; ++j) p[j] = 0.0f;

    const float* W1sel = W1 + idx * (L2C + 1);
    const int e0 = t * 4;
    #pragma unroll
    for (int q = 0; q < 4; ++q) {
        const int e = e0 + q;
        float l0p;
        if (e < 512) {
            const float a0 = clip01(u * s_wp[e]       + th * s_bp[e]);
            const float a1 = clip01(u * s_wp[e + 512] + th * s_bp[e + 512]);
            l0p = a0 * a1;
        } else {
            const int   c   = e - 512;
            const float b0  = clip01(u * s_bp[c] + th * s_wp[c]);
            const float b1v = clip01(u * s_bp[e] + th * s_wp[e]);
            l0p = b0 * b1v;
        }
        l0p *= cc;
        const float* wrow = W1sel + e * W1COLS;
        #pragma unroll
        for (int j = 0; j < 16; ++j) p[j] = fmaf(l0p, wrow[j], p[j]);
    }

    const int lane = t & 63;
    const int wid  = t >> 6;
    #pragma unroll
    for (int j = 0; j < 16; ++j) {
        float v = p[j];
        v += __shfl_down(v, 32);
        v += __shfl_down(v, 16);
        v += __shfl_down(v, 8);
        v += __shfl_down(v, 4);
        v += __shfl_down(v, 2);
        v += __shfl_down(v, 1);
        if (lane == 0) s_red[wid * 16 + j] = v;
    }
    __syncthreads();

    if (t < 16) {
        float x1 = s_red[t] + s_red[16 + t] + s_red[32 + t] + s_red[48 + t]
                 + b1[idx * (L2C + 1) + t];
        if (t == 15) {
            s_l1f = x1;
        } else {
            float cx = clip01(x1);
            s_v[t]       = cx * cx * cc;
            s_v[L2C + t] = cx * cc;
        }
    }
    __syncthreads();

    if (t < L3C) {
        float acc2 = b2[idx * L3C + t];
        #pragma unroll
        for (int r = 0; r < 2 * L2C; ++r)
            acc2 = fmaf(s_v[r], W2[r * W2COLS + idx * L3C + t], acc2);
        s_p2[t] = clip01(acc2) * W3[t * COUNT + idx];
    }
    __syncthreads();

    if (t == 0) {
        float s = 0.0f;
        #pragma unroll
        for (int m = 0; m < L3C; ++m) s += s_p2[m];
        out[b] = s + b3[idx] + s_l1f;
    }
}

// ---- fp32 single-kernel fallback (ws too small) — verified 186 us ----
__global__ __launch_bounds__(BDIM) void nnue_fused_f(
    const float* __restrict__ us,
    const float* __restrict__ them,
    const int*   __restrict__ wi,
    const float* __restrict__ wv,
    const int*   __restrict__ bi,
    const float* __restrict__ bvv,
    const int*   __restrict__ lsi,
    const float* __restrict__ W_ft,
    const float* __restrict__ b_ft,
    const float* __restrict__ W1,
    const float* __restrict__ b1,
    const float* __restrict__ W2,
    const float* __restrict__ b2,
    const float* __restrict__ W3,
    const float* __restrict__ b3,
    float* __restrict__ out)
{
    const int b = blockIdx.x;
    const int t = threadIdx.x;

    __shared__ int   s_idx[2 * K];
    __shared__ float s_val[2 * K];
    __shared__ float s_l0[2 * L1];
    __shared__ float s_red[4 * 16];
    __shared__ float s_v[2 * L2C];
    __shared__ float s_p2[L3C];
    __shared__ float s_l1f;

    if (t < K)          { s_idx[t] = wi[b * K + t];        s_val[t] = wv[b * K + t]; }
    else if (t < 2 * K) { s_idx[t] = bi[b * K + (t - K)];  s_val[t] = bvv[b * K + (t - K)]; }
    __syncthreads();

    const int c4 = t * 4;
    float4 accW = *(const float4*)(b_ft + c4);
    float4 accB = accW;

    #pragma unroll 8
    for (int k = 0; k < K; ++k) {
        const float  vwk = s_val[k];
        const float  vbk = s_val[K + k];
        const float4 rw  = *(const float4*)(W_ft + ((long)s_idx[k]     << 10) + c4);
        const float4 rb  = *(const float4*)(W_ft + ((long)s_idx[K + k] << 10) + c4);
        accW.x = fmaf(vwk, rw.x, accW.x);
        accW.y = fmaf(vwk, rw.y, accW.y);
        accW.z = fmaf(vwk, rw.z, accW.z);
        accW.w = fmaf(vwk, rw.w, accW.w);
        accB.x = fmaf(vbk, rb.x, accB.x);
        accB.y = fmaf(vbk, rb.y, accB.y);
        accB.z = fmaf(vbk, rb.z, accB.z);
        accB.w = fmaf(vbk, rb.w, accB.w);
    }

    const float u  = us[b];
    const float th = them[b];
    float4 A, Bv;
    A.x  = clip01(u * accW.x + th * accB.x);
    A.y  = clip01(u * accW.y + th * accB.y);
    A.z  = clip01(u * accW.z + th * accB.z);
    A.w  = clip01(u * accW.w + th * accB.w);
    Bv.x = clip01(u * accB.x + th * accW.x);
    Bv.y = clip01(u * accB.y + th * accW.y);
    Bv.z = clip01(u * accB.z + th * accW.z);
    Bv.w = clip01(u * accB.w + th * accW.w);
    *(float4*)(s_l0 + c4)      = A;
    *(float4*)(s_l0 + L1 + c4) = Bv;
    __syncthreads();

    const int   idx = lsi[b];
    const float cc  = 127.0f / 128.0f;

    float p[16];
    #pragma unroll
    for (int j = 0; j < 16; ++j) p[j] = 0.0f;

    const float* W1sel = W1 + idx * (L2C + 1);
    #pragma unroll
    for (int q = 0; q < 4; ++q) {
        const int e = c4 + q;
        float l0p;
        if (e < 512) l0p = s_l0[e] * s_l0[e + 512];
        else         l0p = s_l0[e + 512] * s_l0[e + 1024];
        l0p *= cc;
        const float* wrow = W1sel + e * W1COLS;
        #pragma unroll
        for (int j = 0; j < 16; ++j) p[j] = fmaf(l0p, wrow[j], p[j]);
    }

    const int lane = t & 63;
    const int wid  = t >> 6;
    #pragma unroll
    for (int j = 0; j < 16; ++j) {
        float v = p[j];
        v += __shfl_down(v, 32);
        v += __shfl_down(v, 16);
        v += __shfl_down(v, 8);
        v += __shfl_down(v, 4);
        v += __shfl_down(v, 2);
        v += __shfl_down(v, 1);
        if (lane == 0) s_red[wid * 16 + j] = v;
    }
    __syncthreads();

    if (t < 16) {
        float x1 = s_red[t] + s_red[16 + t] + s_red[32 + t] + s_red[48 + t]
                 + b1[idx * (L2C + 1) + t];
        if (t == 15) {
            s_l1f = x1;
        } else {
            float cx = clip01(x1);
            s_v[t]       = cx * cx * cc;
            s_v[L2C + t] = cx * cc;
        }
    }
    __syncthreads();

    if (t < L3C) {
        float acc = b2[idx * L3C + t];
        #pragma unroll
        for (int r = 0; r < 2 * L2C; ++r)
            acc = fmaf(s_v[r], W2[r * W2COLS + idx * L3C + t], acc);
        s_p2[t] = clip01(acc) * W3[t * COUNT + idx];
    }
    __syncthreads();

    if (t == 0) {
        float s = 0.0f;
        #pragma unroll
        for (int m = 0; m < L3C; ++m) s += s_p2[m];
        out[b] = s + b3[idx] + s_l1f;
    }
}

extern "C" void kernel_launch(void* const* d_in, const int* in_sizes, int n_in,
                              void* d_out, int out_size, void* d_ws, size_t ws_size,
                              hipStream_t stream) {
    const float* us   = (const float*)d_in[0];
    const float* them = (const float*)d_in[1];
    const int*   wi   = (const int*)  d_in[2];
    const float* wv   = (const float*)d_in[3];
    const int*   bi   = (const int*)  d_in[4];
    const float* bv   = (const float*)d_in[5];
    const int*   lsi  = (const int*)  d_in[6];
    const float* W_ft = (const float*)d_in[7];
    const float* b_ft = (const float*)d_in[8];
    const float* W1   = (const float*)d_in[9];
    const float* b1   = (const float*)d_in[10];
    const float* W2   = (const float*)d_in[11];
    const float* b2   = (const float*)d_in[12];
    const float* W3   = (const float*)d_in[13];
    const float* b3   = (const float*)d_in[14];
    float*       out  = (float*)d_out;

    const int Bn = in_sizes[0]; // 4096 batch rows
    const size_t qTableBytes = (size_t)NF * L1;                  // 23.1 MB
    const size_t needed      = qTableBytes + (size_t)NF * sizeof(float);

    if (ws_size >= needed) {
        unsigned char* Wq  = (unsigned char*)d_ws;
        float*         scl = (float*)((char*)d_ws + qTableBytes);
        quant_w_ft<<<(NF + 3) / 4, 256, 0, stream>>>(W_ft, Wq, scl, NF);
        nnue_fused_q<<<Bn, BDIM, 0, stream>>>(us, them, wi, wv, bi, bv, lsi,
                                              Wq, scl, b_ft, W1, b1, W2, b2, W3, b3, out);
    } else {
        nnue_fused_f<<<Bn, BDIM, 0, stream>>>(us, them, wi, wv, bi, bv, lsi,
                                              W_ft, b_ft, W1, b1, W2, b2, W3, b3, out);
    }
}